// Round 1
// baseline (794.379 us; speedup 1.0000x reference)
//
#include <hip/hip_runtime.h>

#define BS_TOTAL 32768   // B*S
#define DB 768
#define EPAD 64          // ent slab padded 50 -> 64
#define KV 832           // DB + EPAD (virtual K)
#define KREAL 818        // real K (cols >= 818 are zero)
#define TT 68
#define SEQ 512

// ---------------- K0: ent = sum_k entity_table[entities_x[...,k]] -> [32768][64] (cols 50..63 zero)
__global__ __launch_bounds__(256) void ent_kernel(
    const int* __restrict__ ex, const float* __restrict__ table,
    float* __restrict__ entw)
{
    int g = blockIdx.x * 256 + threadIdx.x;   // 32768*64 threads
    int bs = g >> 6;
    int e = g & 63;
    float v = 0.f;
    if (e < 50) {
        int base = bs * 3;
        int i0 = ex[base], i1 = ex[base + 1], i2 = ex[base + 2];
        v = table[i0 * 50 + e] + table[i1 * 50 + e] + table[i2 * 50 + e];
    }
    entw[g] = v;
}

// ---------------- K1: x = relu(concat(enc, ent) @ W^T + b)  [32768][768]
// 128x128 tile, BK=16, 256 threads, 8x8 per thread, fp32
__global__ __launch_bounds__(256) void fc1_gemm(
    const float* __restrict__ enc, const float* __restrict__ entw,
    const float* __restrict__ W, const float* __restrict__ bias,
    float* __restrict__ xout)
{
    __shared__ float As[16 * 132];
    __shared__ float Bs[16 * 132];
    const int t = threadIdx.x;
    const int bm0 = blockIdx.x * 128;
    const int bn0 = blockIdx.y * 128;
    const int tx = t & 15, ty = t >> 4;

    float bias_r[8];
#pragma unroll
    for (int mm = 0; mm < 2; ++mm)
#pragma unroll
        for (int j = 0; j < 4; ++j)
            bias_r[mm * 4 + j] = bias[bn0 + mm * 64 + tx * 4 + j];

    float acc[8][8];
#pragma unroll
    for (int i = 0; i < 8; ++i)
#pragma unroll
        for (int j = 0; j < 8; ++j) acc[i][j] = 0.f;

    for (int k0 = 0; k0 < KV; k0 += 16) {
        // A tile: 128 rows x 16 k, float4 chunks (512), 2 per thread
#pragma unroll
        for (int i = 0; i < 2; ++i) {
            int cid = t + i * 256;
            int r = cid >> 2;
            int c4 = (cid & 3) << 2;
            int row = bm0 + r;
            float4 v;
            if (k0 < DB) {
                v = *reinterpret_cast<const float4*>(enc + (size_t)row * DB + k0 + c4);
            } else {
                v = *reinterpret_cast<const float4*>(entw + ((size_t)row << 6) + (k0 - DB) + c4);
            }
            As[(c4 + 0) * 132 + r] = v.x;
            As[(c4 + 1) * 132 + r] = v.y;
            As[(c4 + 2) * 132 + r] = v.z;
            As[(c4 + 3) * 132 + r] = v.w;
        }
        // B tile: Bs[kk][n] = W[(bn0+n)*818 + k0+kk] (zero if k>=818), float2 chunks (1024), 4/thread
#pragma unroll
        for (int i = 0; i < 4; ++i) {
            int cid = t + i * 256;
            int n = cid >> 3;
            int c2 = (cid & 7) << 1;
            int kg = k0 + c2;
            float2 v = make_float2(0.f, 0.f);
            if (kg < KREAL)
                v = *reinterpret_cast<const float2*>(W + (size_t)(bn0 + n) * KREAL + kg);
            Bs[(c2 + 0) * 132 + n] = v.x;
            Bs[(c2 + 1) * 132 + n] = v.y;
        }
        __syncthreads();
#pragma unroll
        for (int kk = 0; kk < 16; ++kk) {
            const float* Ar = As + kk * 132;
            const float* Br = Bs + kk * 132;
            float4 a0 = *reinterpret_cast<const float4*>(Ar + ty * 8);
            float4 a1 = *reinterpret_cast<const float4*>(Ar + ty * 8 + 4);
            float4 b0 = *reinterpret_cast<const float4*>(Br + tx * 4);
            float4 b1 = *reinterpret_cast<const float4*>(Br + 64 + tx * 4);
            float a[8] = {a0.x, a0.y, a0.z, a0.w, a1.x, a1.y, a1.z, a1.w};
            float bb[8] = {b0.x, b0.y, b0.z, b0.w, b1.x, b1.y, b1.z, b1.w};
#pragma unroll
            for (int i = 0; i < 8; ++i)
#pragma unroll
                for (int j = 0; j < 8; ++j)
                    acc[i][j] += a[i] * bb[j];
        }
        __syncthreads();
    }
    // epilogue: bias + relu, float4 stores
#pragma unroll
    for (int i = 0; i < 8; ++i) {
        size_t row = (size_t)(bm0 + ty * 8 + i);
#pragma unroll
        for (int mm = 0; mm < 2; ++mm) {
            float4 o;
            o.x = fmaxf(acc[i][mm * 4 + 0] + bias_r[mm * 4 + 0], 0.f);
            o.y = fmaxf(acc[i][mm * 4 + 1] + bias_r[mm * 4 + 1], 0.f);
            o.z = fmaxf(acc[i][mm * 4 + 2] + bias_r[mm * 4 + 2], 0.f);
            o.w = fmaxf(acc[i][mm * 4 + 3] + bias_r[mm * 4 + 3], 0.f);
            *reinterpret_cast<float4*>(xout + row * DB + bn0 + mm * 64 + tx * 4) = o;
        }
    }
}

// ---------------- K2: gathered trig GEMM + bias + argmax
// 64 rows/block, 256 threads (tx:16 cols-groups, ty:16 row-groups of 4), N padded to 80
__global__ __launch_bounds__(256) void trig_kernel(
    const float* __restrict__ xfc, const int* __restrict__ head_idx,
    const float* __restrict__ Wt, const float* __restrict__ bt,
    float* __restrict__ logits, float* __restrict__ hat)
{
    __shared__ float Xs[32 * 68];   // [kk][row], stride 68
    __shared__ float Ws[32 * 80];   // [kk][n],   stride 80, n>=68 zero
    __shared__ int srow[64];
    const int t = threadIdx.x;
    const int s0 = blockIdx.x * 64;
    if (t < 64) {
        int sg = s0 + t;
        int b = sg >> 9;
        srow[t] = (b << 9) + head_idx[sg];
    }
    __syncthreads();
    const int tx = t & 15, ty = t >> 4;
    float acc[4][5];
#pragma unroll
    for (int i = 0; i < 4; ++i)
#pragma unroll
        for (int m = 0; m < 5; ++m) acc[i][m] = 0.f;

    for (int k0 = 0; k0 < DB; k0 += 32) {
        // stage X: 64 rows x 32 k = 512 float4, 2/thread
#pragma unroll
        for (int i = 0; i < 2; ++i) {
            int cid = t + i * 256;
            int r = cid >> 3;
            int c4 = (cid & 7) << 2;
            float4 v = *reinterpret_cast<const float4*>(xfc + (size_t)srow[r] * DB + k0 + c4);
            Xs[(c4 + 0) * 68 + r] = v.x;
            Xs[(c4 + 1) * 68 + r] = v.y;
            Xs[(c4 + 2) * 68 + r] = v.z;
            Xs[(c4 + 3) * 68 + r] = v.w;
        }
        // stage W^T: 32 k x 80 n = 2560, 10/thread, coalesced along k
#pragma unroll
        for (int i = 0; i < 10; ++i) {
            int e = t + i * 256;
            int kk = e & 31;
            int n = e >> 5;
            float v = (n < TT) ? Wt[(size_t)n * DB + k0 + kk] : 0.f;
            Ws[kk * 80 + n] = v;
        }
        __syncthreads();
#pragma unroll
        for (int kk = 0; kk < 32; ++kk) {
            float4 a = *reinterpret_cast<const float4*>(Xs + kk * 68 + ty * 4);
            float w[5];
#pragma unroll
            for (int m = 0; m < 5; ++m) w[m] = Ws[kk * 80 + tx + 16 * m];
            float av[4] = {a.x, a.y, a.z, a.w};
#pragma unroll
            for (int i = 0; i < 4; ++i)
#pragma unroll
                for (int m = 0; m < 5; ++m)
                    acc[i][m] += av[i] * w[m];
        }
        __syncthreads();
    }
    // epilogue: bias, store logits, first-index argmax
#pragma unroll
    for (int i = 0; i < 4; ++i) {
        int row = s0 + ty * 4 + i;
        float bestv = -1e38f;
        int besti = 0;
#pragma unroll
        for (int m = 0; m < 5; ++m) {
            int col = tx + 16 * m;
            float v = -1e38f;
            if (col < TT) {
                v = acc[i][m] + bt[col];
                logits[(size_t)row * TT + col] = v;
            }
            if (v > bestv) { bestv = v; besti = col; }   // cols ascending in m -> first-max kept
        }
#pragma unroll
        for (int off = 8; off > 0; off >>= 1) {
            float ov = __shfl_xor(bestv, off, 16);
            int oi = __shfl_xor(besti, off, 16);
            if (ov > bestv || (ov == bestv && oi < besti)) { bestv = ov; besti = oi; }
        }
        if (tx == 0) hat[row] = (float)besti;
    }
}

// ---------------- K3a: span-mean pooling -> pooled[64][24][768] (0..7 trig, 8..23 cand)
__global__ __launch_bounds__(256) void pool_kernel(
    const float* __restrict__ xfc, const int* __restrict__ head_idx,
    const int* __restrict__ cand_spans, const int* __restrict__ trig_spans,
    float* __restrict__ pooled)
{
    const int b = blockIdx.x;
    __shared__ int rows_s[24][8];
    __shared__ int lens[24];
    __shared__ float invlen[24];
    const int t = threadIdx.x;
    if (t < 24) {
        const int* sp = (t < 8) ? (trig_spans + (b * 8 + t) * 2)
                                : (cand_spans + (b * 16 + (t - 8)) * 2);
        int st = sp[0], en = sp[1];
        int len = en - st;
        if (len < 0) len = 0;
        if (len > 8) len = 8;
        lens[t] = len;
        invlen[t] = 1.f / (float)(len > 0 ? len : 1);
        for (int p = 0; p < len; ++p)
            rows_s[t][p] = (b << 9) + head_idx[(b << 9) + st + p];
    }
    __syncthreads();
    for (int idx = t; idx < 24 * DB; idx += 256) {
        int n = idx / DB;
        int d = idx - n * DB;
        int len = lens[n];
        float s = 0.f;
        for (int p = 0; p < len; ++p)
            s += xfc[(size_t)rows_s[n][p] * DB + d];
        pooled[((size_t)b * 24 + n) * DB + d] = s * invlen[n];
    }
}

// ---------------- K3b: argument_hidden broadcast write [64][8][16][1536], float4 per thread
__global__ __launch_bounds__(256) void arg_kernel(
    const float* __restrict__ pooled, float* __restrict__ out2)
{
    int g = blockIdx.x * 256 + threadIdx.x;    // < 3145728 float4s
    int b = g / 49152;                          // 8*16*1536/4
    int rem = g - b * 49152;
    int pair = rem / 384;                       // 1536/4
    int off4 = rem - pair * 384;
    int ti = pair >> 4;
    int c = pair & 15;
    int col = off4 << 2;
    const float* src;
    if (col < DB) src = pooled + ((size_t)(b * 24 + ti)) * DB + col;
    else          src = pooled + ((size_t)(b * 24 + 8 + c)) * DB + (col - DB);
    float4 v = *reinterpret_cast<const float4*>(src);
    *reinterpret_cast<float4*>(out2 + ((size_t)g << 2)) = v;
}

extern "C" void kernel_launch(void* const* d_in, const int* in_sizes, int n_in,
                              void* d_out, int out_size, void* d_ws, size_t ws_size,
                              hipStream_t stream)
{
    const float* enc   = (const float*)d_in[0];
    const float* table = (const float*)d_in[1];
    const float* fc1w  = (const float*)d_in[2];
    const float* fc1b  = (const float*)d_in[3];
    const float* trigw = (const float*)d_in[4];
    const float* trigb = (const float*)d_in[5];
    const int*   ex    = (const int*)d_in[6];
    const int*   hidx  = (const int*)d_in[7];
    const int*   cspan = (const int*)d_in[8];
    const int*   tspan = (const int*)d_in[9];

    float* out0 = (float*)d_out;                        // trigger_logits [64,512,68]
    float* out1 = out0 + (size_t)BS_TOTAL * TT;         // trigger_hat    [64,512] (as float)
    float* out2 = out1 + BS_TOTAL;                      // argument_hidden [64,8,16,1536]

    float* ws_ent  = (float*)d_ws;                      // [32768][64]
    float* ws_xfc  = ws_ent + (size_t)BS_TOTAL * EPAD;  // [32768][768]
    float* ws_pool = ws_xfc + (size_t)BS_TOTAL * DB;    // [64][24][768]

    ent_kernel<<<dim3(BS_TOTAL * EPAD / 256), dim3(256), 0, stream>>>(ex, table, ws_ent);
    fc1_gemm<<<dim3(BS_TOTAL / 128, DB / 128), dim3(256), 0, stream>>>(enc, ws_ent, fc1w, fc1b, ws_xfc);
    trig_kernel<<<dim3(BS_TOTAL / 64), dim3(256), 0, stream>>>(ws_xfc, hidx, trigw, trigb, out0, out1);
    pool_kernel<<<dim3(64), dim3(256), 0, stream>>>(ws_xfc, hidx, cspan, tspan, ws_pool);
    arg_kernel<<<dim3(3145728 / 256), dim3(256), 0, stream>>>(ws_pool, out2);
}

// Round 2
// 788.313 us; speedup vs baseline: 1.0077x; 1.0077x over previous
//
#include <hip/hip_runtime.h>

#define BS_TOTAL 32768   // B*S
#define DB 768
#define EPAD 64          // ent slab padded 50 -> 64
#define KV 832           // DB + EPAD (virtual K)
#define KREAL 818        // real K (cols >= 818 are zero)
#define TT 68
#define SEQ 512

typedef float v2f __attribute__((ext_vector_type(2)));
union F4 { float4 q; v2f h[2]; float f[4]; };

// packed fp32 fma: acc(pair) += broadcast(a.lo or a.hi) * b(pair)
#define PK_LO(acc, a, b) asm("v_pk_fma_f32 %0, %1, %2, %0 op_sel:[0,0,0] op_sel_hi:[0,1,1]" : "+v"(acc) : "v"(a), "v"(b))
#define PK_HI(acc, a, b) asm("v_pk_fma_f32 %0, %1, %2, %0 op_sel:[1,0,0] op_sel_hi:[1,1,1]" : "+v"(acc) : "v"(a), "v"(b))

// ---------------- K0: ent = sum_k entity_table[entities_x[...,k]] -> [32768][64]
__global__ __launch_bounds__(256) void ent_kernel(
    const int* __restrict__ ex, const float* __restrict__ table,
    float* __restrict__ entw)
{
    int g = blockIdx.x * 256 + threadIdx.x;
    int bs = g >> 6;
    int e = g & 63;
    float v = 0.f;
    if (e < 50) {
        int base = bs * 3;
        int i0 = ex[base], i1 = ex[base + 1], i2 = ex[base + 2];
        v = table[i0 * 50 + e] + table[i1 * 50 + e] + table[i2 * 50 + e];
    }
    entw[g] = v;
}

// ---------------- K1: x = relu(concat(enc, ent) @ W^T + b)  [32768][768]
// 128x128 tile, BK=32, 256 threads, 8 rows x 4 col-pairs per thread,
// register-prefetch single-LDS-buffer pipeline, v_pk_fma_f32 inner loop.
__global__ __launch_bounds__(256, 4) void fc1_gemm(
    const float* __restrict__ enc, const float* __restrict__ entw,
    const float* __restrict__ W, const float* __restrict__ bias,
    float* __restrict__ xout)
{
    __shared__ float As[32 * 132];
    __shared__ float Bs[32 * 132];
    const int t = threadIdx.x;
    const int bn0 = blockIdx.x * 128;   // N outer: consecutive blocks share A panel
    const int bm0 = blockIdx.y * 128;
    const int tx = t & 15, ty = t >> 4;

    v2f acc[8][4];
#pragma unroll
    for (int i = 0; i < 8; ++i)
#pragma unroll
        for (int p = 0; p < 4; ++p) acc[i][p] = (v2f){0.f, 0.f};

    float4 pA[4];
    float2 pB[8];

#define LOADA(IT) {                                                         \
    int k0_ = (IT) * 32;                                                    \
    _Pragma("unroll")                                                       \
    for (int i_ = 0; i_ < 4; ++i_) {                                        \
        int cid_ = t + i_ * 256;                                            \
        int r_ = cid_ >> 3;                                                 \
        int c4_ = (cid_ & 7) << 2;                                          \
        int k_ = k0_ + c4_;                                                 \
        int row_ = bm0 + r_;                                                \
        pA[i_] = (k_ < DB)                                                  \
            ? *reinterpret_cast<const float4*>(enc + (size_t)row_ * DB + k_)\
            : *reinterpret_cast<const float4*>(entw + ((size_t)row_ << 6) + (k_ - DB)); } }

#define LOADB(IT) {                                                         \
    int k0_ = (IT) * 32;                                                    \
    _Pragma("unroll")                                                       \
    for (int i_ = 0; i_ < 8; ++i_) {                                        \
        int cid_ = t + i_ * 256;                                            \
        int n_ = cid_ >> 4;                                                 \
        int c2_ = (cid_ & 15) << 1;                                         \
        int kg_ = k0_ + c2_;                                                \
        pB[i_] = (kg_ < KREAL)                                              \
            ? *reinterpret_cast<const float2*>(W + (size_t)(bn0 + n_) * KREAL + kg_) \
            : make_float2(0.f, 0.f); } }

    LOADA(0); LOADB(0);

    for (int it = 0; it < 26; ++it) {
        __syncthreads();
        // LDS stores (transposed [k][m])
#pragma unroll
        for (int i = 0; i < 4; ++i) {
            int cid = t + i * 256;
            int r = cid >> 3;
            int c4 = (cid & 7) << 2;
            As[(c4 + 0) * 132 + r] = pA[i].x;
            As[(c4 + 1) * 132 + r] = pA[i].y;
            As[(c4 + 2) * 132 + r] = pA[i].z;
            As[(c4 + 3) * 132 + r] = pA[i].w;
        }
#pragma unroll
        for (int i = 0; i < 8; ++i) {
            int cid = t + i * 256;
            int n = cid >> 4;
            int c2 = (cid & 15) << 1;
            Bs[(c2 + 0) * 132 + n] = pB[i].x;
            Bs[(c2 + 1) * 132 + n] = pB[i].y;
        }
        if (it < 25) { LOADA(it + 1); LOADB(it + 1); }  // prefetch overlaps compute
        __syncthreads();
#pragma unroll
        for (int kk = 0; kk < 32; ++kk) {
            const float* Ar = As + kk * 132 + ty * 8;
            const float* Br = Bs + kk * 132 + tx * 4;
            F4 a0, a1, b0, b1;
            a0.q = *reinterpret_cast<const float4*>(Ar);
            a1.q = *reinterpret_cast<const float4*>(Ar + 4);
            b0.q = *reinterpret_cast<const float4*>(Br);
            b1.q = *reinterpret_cast<const float4*>(Br + 64);
#define ROWPK(I, AH)                                                     \
            PK_LO(acc[I][0], AH, b0.h[0]); PK_LO(acc[I][1], AH, b0.h[1]);\
            PK_LO(acc[I][2], AH, b1.h[0]); PK_LO(acc[I][3], AH, b1.h[1]);\
            PK_HI(acc[I+1][0], AH, b0.h[0]); PK_HI(acc[I+1][1], AH, b0.h[1]);\
            PK_HI(acc[I+1][2], AH, b1.h[0]); PK_HI(acc[I+1][3], AH, b1.h[1]);
            ROWPK(0, a0.h[0]) ROWPK(2, a0.h[1]) ROWPK(4, a1.h[0]) ROWPK(6, a1.h[1])
#undef ROWPK
        }
    }

    float4 bias0 = *reinterpret_cast<const float4*>(bias + bn0 + tx * 4);
    float4 bias1 = *reinterpret_cast<const float4*>(bias + bn0 + 64 + tx * 4);
#pragma unroll
    for (int i = 0; i < 8; ++i) {
        size_t row = (size_t)(bm0 + ty * 8 + i);
        float4 o;
        o.x = fmaxf(acc[i][0].x + bias0.x, 0.f);
        o.y = fmaxf(acc[i][0].y + bias0.y, 0.f);
        o.z = fmaxf(acc[i][1].x + bias0.z, 0.f);
        o.w = fmaxf(acc[i][1].y + bias0.w, 0.f);
        *reinterpret_cast<float4*>(xout + row * DB + bn0 + tx * 4) = o;
        o.x = fmaxf(acc[i][2].x + bias1.x, 0.f);
        o.y = fmaxf(acc[i][2].y + bias1.y, 0.f);
        o.z = fmaxf(acc[i][3].x + bias1.z, 0.f);
        o.w = fmaxf(acc[i][3].y + bias1.w, 0.f);
        *reinterpret_cast<float4*>(xout + row * DB + bn0 + 64 + tx * 4) = o;
    }
}

// ---------------- K2: gathered trig GEMM + bias + argmax
// 32 rows/block (1024 blocks), 256 threads: tx 0..15 col-groups, ty 0..15 -> 2 rows
__global__ __launch_bounds__(256) void trig_kernel(
    const float* __restrict__ xfc, const int* __restrict__ head_idx,
    const float* __restrict__ Wt, const float* __restrict__ bt,
    float* __restrict__ logits, float* __restrict__ hat)
{
    __shared__ float Xs[32 * 36];   // [kk][row], 32 rows + 4 pad
    __shared__ float Ws[32 * 80];   // [kk][n], n>=68 zero
    __shared__ int srow[32];
    const int t = threadIdx.x;
    const int s0 = blockIdx.x * 32;
    if (t < 32) {
        int sg = s0 + t;
        int b = sg >> 9;
        srow[t] = (b << 9) + head_idx[sg];
    }
    __syncthreads();
    const int tx = t & 15, ty = t >> 4;
    float acc[2][5];
#pragma unroll
    for (int i = 0; i < 2; ++i)
#pragma unroll
        for (int m = 0; m < 5; ++m) acc[i][m] = 0.f;

    for (int k0 = 0; k0 < DB; k0 += 32) {
        // stage X: 32 rows x 32 k = 256 float4, 1/thread
        {
            int r = t >> 3;
            int c4 = (t & 7) << 2;
            float4 v = *reinterpret_cast<const float4*>(xfc + (size_t)srow[r] * DB + k0 + c4);
            Xs[(c4 + 0) * 36 + r] = v.x;
            Xs[(c4 + 1) * 36 + r] = v.y;
            Xs[(c4 + 2) * 36 + r] = v.z;
            Xs[(c4 + 3) * 36 + r] = v.w;
        }
        // stage W^T: 32 k x 80 n = 2560, 10/thread
#pragma unroll
        for (int i = 0; i < 10; ++i) {
            int e = t + i * 256;
            int kk = e & 31;
            int n = e >> 5;
            float v = (n < TT) ? Wt[(size_t)n * DB + k0 + kk] : 0.f;
            Ws[kk * 80 + n] = v;
        }
        __syncthreads();
#pragma unroll
        for (int kk = 0; kk < 32; ++kk) {
            v2f xa = *reinterpret_cast<const v2f*>(Xs + kk * 36 + ty * 2);
            float w[5];
#pragma unroll
            for (int m = 0; m < 5; ++m) w[m] = Ws[kk * 80 + tx + 16 * m];
#pragma unroll
            for (int m = 0; m < 5; ++m) {
                acc[0][m] += xa.x * w[m];
                acc[1][m] += xa.y * w[m];
            }
        }
        __syncthreads();
    }
#pragma unroll
    for (int i = 0; i < 2; ++i) {
        int row = s0 + ty * 2 + i;
        float bestv = -1e38f;
        int besti = 0;
#pragma unroll
        for (int m = 0; m < 5; ++m) {
            int col = tx + 16 * m;
            float v = -1e38f;
            if (col < TT) {
                v = acc[i][m] + bt[col];
                logits[(size_t)row * TT + col] = v;
            }
            if (v > bestv) { bestv = v; besti = col; }
        }
#pragma unroll
        for (int off = 8; off > 0; off >>= 1) {
            float ov = __shfl_xor(bestv, off, 16);
            int oi = __shfl_xor(besti, off, 16);
            if (ov > bestv || (ov == bestv && oi < besti)) { bestv = ov; besti = oi; }
        }
        if (tx == 0) hat[row] = (float)besti;
    }
}

// ---------------- K3a: span-mean pooling -> pooled[64][24][768]
__global__ __launch_bounds__(256) void pool_kernel(
    const float* __restrict__ xfc, const int* __restrict__ head_idx,
    const int* __restrict__ cand_spans, const int* __restrict__ trig_spans,
    float* __restrict__ pooled)
{
    const int b = blockIdx.x;
    __shared__ int rows_s[24][8];
    __shared__ int lens[24];
    __shared__ float invlen[24];
    const int t = threadIdx.x;
    if (t < 24) {
        const int* sp = (t < 8) ? (trig_spans + (b * 8 + t) * 2)
                                : (cand_spans + (b * 16 + (t - 8)) * 2);
        int st = sp[0], en = sp[1];
        int len = en - st;
        if (len < 0) len = 0;
        if (len > 8) len = 8;
        lens[t] = len;
        invlen[t] = 1.f / (float)(len > 0 ? len : 1);
        for (int p = 0; p < len; ++p)
            rows_s[t][p] = (b << 9) + head_idx[(b << 9) + st + p];
    }
    __syncthreads();
    for (int idx = t; idx < 24 * DB; idx += 256) {
        int n = idx / DB;
        int d = idx - n * DB;
        int len = lens[n];
        float s = 0.f;
        for (int p = 0; p < len; ++p)
            s += xfc[(size_t)rows_s[n][p] * DB + d];
        pooled[((size_t)b * 24 + n) * DB + d] = s * invlen[n];
    }
}

// ---------------- K3b: argument_hidden broadcast write [64][8][16][1536]
__global__ __launch_bounds__(256) void arg_kernel(
    const float* __restrict__ pooled, float* __restrict__ out2)
{
    int g = blockIdx.x * 256 + threadIdx.x;
    int b = g / 49152;
    int rem = g - b * 49152;
    int pair = rem / 384;
    int off4 = rem - pair * 384;
    int ti = pair >> 4;
    int c = pair & 15;
    int col = off4 << 2;
    const float* src;
    if (col < DB) src = pooled + ((size_t)(b * 24 + ti)) * DB + col;
    else          src = pooled + ((size_t)(b * 24 + 8 + c)) * DB + (col - DB);
    float4 v = *reinterpret_cast<const float4*>(src);
    *reinterpret_cast<float4*>(out2 + ((size_t)g << 2)) = v;
}

extern "C" void kernel_launch(void* const* d_in, const int* in_sizes, int n_in,
                              void* d_out, int out_size, void* d_ws, size_t ws_size,
                              hipStream_t stream)
{
    const float* enc   = (const float*)d_in[0];
    const float* table = (const float*)d_in[1];
    const float* fc1w  = (const float*)d_in[2];
    const float* fc1b  = (const float*)d_in[3];
    const float* trigw = (const float*)d_in[4];
    const float* trigb = (const float*)d_in[5];
    const int*   ex    = (const int*)d_in[6];
    const int*   hidx  = (const int*)d_in[7];
    const int*   cspan = (const int*)d_in[8];
    const int*   tspan = (const int*)d_in[9];

    float* out0 = (float*)d_out;
    float* out1 = out0 + (size_t)BS_TOTAL * TT;
    float* out2 = out1 + BS_TOTAL;

    float* ws_ent  = (float*)d_ws;
    float* ws_xfc  = ws_ent + (size_t)BS_TOTAL * EPAD;
    float* ws_pool = ws_xfc + (size_t)BS_TOTAL * DB;

    ent_kernel<<<dim3(BS_TOTAL * EPAD / 256), dim3(256), 0, stream>>>(ex, table, ws_ent);
    fc1_gemm<<<dim3(DB / 128, BS_TOTAL / 128), dim3(256), 0, stream>>>(enc, ws_ent, fc1w, fc1b, ws_xfc);
    trig_kernel<<<dim3(BS_TOTAL / 32), dim3(256), 0, stream>>>(ws_xfc, hidx, trigw, trigb, out0, out1);
    pool_kernel<<<dim3(64), dim3(256), 0, stream>>>(ws_xfc, hidx, cspan, tspan, ws_pool);
    arg_kernel<<<dim3(3145728 / 256), dim3(256), 0, stream>>>(ws_pool, out2);
}

// Round 3
// 787.352 us; speedup vs baseline: 1.0089x; 1.0012x over previous
//
#include <hip/hip_runtime.h>

#define BS_TOTAL 32768   // B*S
#define DB 768
#define EPAD 64          // ent slab padded 50 -> 64
#define KV 832           // DB + EPAD (virtual K)
#define KREAL 818        // real K (cols >= 818 are zero)
#define TT 68
#define SEQ 512

typedef float v2f __attribute__((ext_vector_type(2)));
union F4 { float4 q; v2f h[2]; float f[4]; };

// packed fp32 fma: acc(pair) += broadcast(a.lo or a.hi) * b(pair)
#define PK_LO(acc, a, b) asm("v_pk_fma_f32 %0, %1, %2, %0 op_sel:[0,0,0] op_sel_hi:[0,1,1]" : "+v"(acc) : "v"(a), "v"(b))
#define PK_HI(acc, a, b) asm("v_pk_fma_f32 %0, %1, %2, %0 op_sel:[1,0,0] op_sel_hi:[1,1,1]" : "+v"(acc) : "v"(a), "v"(b))

// ---------------- K0: ent = sum_k entity_table[entities_x[...,k]] -> [32768][64]
__global__ __launch_bounds__(256) void ent_kernel(
    const int* __restrict__ ex, const float* __restrict__ table,
    float* __restrict__ entw)
{
    int g = blockIdx.x * 256 + threadIdx.x;
    int bs = g >> 6;
    int e = g & 63;
    float v = 0.f;
    if (e < 50) {
        int base = bs * 3;
        int i0 = ex[base], i1 = ex[base + 1], i2 = ex[base + 2];
        v = table[i0 * 50 + e] + table[i1 * 50 + e] + table[i2 * 50 + e];
    }
    entw[g] = v;
}

// ---------------- K1: x = relu(concat(enc, ent) @ W^T + b)  [32768][768]
// 128x128 tile, BK=32, 256 threads, 8 rows x 4 col-pairs per thread,
// register-prefetch single-LDS-buffer pipeline, v_pk_fma_f32 inner loop.
__global__ __launch_bounds__(256, 4) void fc1_gemm(
    const float* __restrict__ enc, const float* __restrict__ entw,
    const float* __restrict__ W, const float* __restrict__ bias,
    float* __restrict__ xout)
{
    __shared__ float As[32 * 132];
    __shared__ float Bs[32 * 132];
    const int t = threadIdx.x;
    const int bn0 = blockIdx.x * 128;   // N outer: consecutive blocks share A panel
    const int bm0 = blockIdx.y * 128;
    const int tx = t & 15, ty = t >> 4;

    v2f acc[8][4];
#pragma unroll
    for (int i = 0; i < 8; ++i)
#pragma unroll
        for (int p = 0; p < 4; ++p) acc[i][p] = (v2f){0.f, 0.f};

    float4 pA[4];
    float2 pB[8];

#define LOADA(IT) {                                                         \
    int k0_ = (IT) * 32;                                                    \
    _Pragma("unroll")                                                       \
    for (int i_ = 0; i_ < 4; ++i_) {                                        \
        int cid_ = t + i_ * 256;                                            \
        int r_ = cid_ >> 3;                                                 \
        int c4_ = (cid_ & 7) << 2;                                          \
        int k_ = k0_ + c4_;                                                 \
        int row_ = bm0 + r_;                                                \
        pA[i_] = (k_ < DB)                                                  \
            ? *reinterpret_cast<const float4*>(enc + (size_t)row_ * DB + k_)\
            : *reinterpret_cast<const float4*>(entw + ((size_t)row_ << 6) + (k_ - DB)); } }

#define LOADB(IT) {                                                         \
    int k0_ = (IT) * 32;                                                    \
    _Pragma("unroll")                                                       \
    for (int i_ = 0; i_ < 8; ++i_) {                                        \
        int cid_ = t + i_ * 256;                                            \
        int n_ = cid_ >> 4;                                                 \
        int c2_ = (cid_ & 15) << 1;                                         \
        int kg_ = k0_ + c2_;                                                \
        pB[i_] = (kg_ < KREAL)                                              \
            ? *reinterpret_cast<const float2*>(W + (size_t)(bn0 + n_) * KREAL + kg_) \
            : make_float2(0.f, 0.f); } }

    LOADA(0); LOADB(0);

    for (int it = 0; it < 26; ++it) {
        __syncthreads();
        // LDS stores (transposed [k][m])
#pragma unroll
        for (int i = 0; i < 4; ++i) {
            int cid = t + i * 256;
            int r = cid >> 3;
            int c4 = (cid & 7) << 2;
            As[(c4 + 0) * 132 + r] = pA[i].x;
            As[(c4 + 1) * 132 + r] = pA[i].y;
            As[(c4 + 2) * 132 + r] = pA[i].z;
            As[(c4 + 3) * 132 + r] = pA[i].w;
        }
#pragma unroll
        for (int i = 0; i < 8; ++i) {
            int cid = t + i * 256;
            int n = cid >> 4;
            int c2 = (cid & 15) << 1;
            Bs[(c2 + 0) * 132 + n] = pB[i].x;
            Bs[(c2 + 1) * 132 + n] = pB[i].y;
        }
        if (it < 25) { LOADA(it + 1); LOADB(it + 1); }  // prefetch overlaps compute
        __syncthreads();
#pragma unroll
        for (int kk = 0; kk < 32; ++kk) {
            const float* Ar = As + kk * 132 + ty * 8;
            const float* Br = Bs + kk * 132 + tx * 4;
            F4 a0, a1, b0, b1;
            a0.q = *reinterpret_cast<const float4*>(Ar);
            a1.q = *reinterpret_cast<const float4*>(Ar + 4);
            b0.q = *reinterpret_cast<const float4*>(Br);
            b1.q = *reinterpret_cast<const float4*>(Br + 64);
#define ROWPK(I, AH)                                                     \
            PK_LO(acc[I][0], AH, b0.h[0]); PK_LO(acc[I][1], AH, b0.h[1]);\
            PK_LO(acc[I][2], AH, b1.h[0]); PK_LO(acc[I][3], AH, b1.h[1]);\
            PK_HI(acc[I+1][0], AH, b0.h[0]); PK_HI(acc[I+1][1], AH, b0.h[1]);\
            PK_HI(acc[I+1][2], AH, b1.h[0]); PK_HI(acc[I+1][3], AH, b1.h[1]);
            ROWPK(0, a0.h[0]) ROWPK(2, a0.h[1]) ROWPK(4, a1.h[0]) ROWPK(6, a1.h[1])
#undef ROWPK
        }
    }

    float4 bias0 = *reinterpret_cast<const float4*>(bias + bn0 + tx * 4);
    float4 bias1 = *reinterpret_cast<const float4*>(bias + bn0 + 64 + tx * 4);
#pragma unroll
    for (int i = 0; i < 8; ++i) {
        size_t row = (size_t)(bm0 + ty * 8 + i);
        float4 o;
        o.x = fmaxf(acc[i][0].x + bias0.x, 0.f);
        o.y = fmaxf(acc[i][0].y + bias0.y, 0.f);
        o.z = fmaxf(acc[i][1].x + bias0.z, 0.f);
        o.w = fmaxf(acc[i][1].y + bias0.w, 0.f);
        *reinterpret_cast<float4*>(xout + row * DB + bn0 + tx * 4) = o;
        o.x = fmaxf(acc[i][2].x + bias1.x, 0.f);
        o.y = fmaxf(acc[i][2].y + bias1.y, 0.f);
        o.z = fmaxf(acc[i][3].x + bias1.z, 0.f);
        o.w = fmaxf(acc[i][3].y + bias1.w, 0.f);
        *reinterpret_cast<float4*>(xout + row * DB + bn0 + 64 + tx * 4) = o;
    }
}

// ---------------- K2: gathered trig GEMM + bias + argmax
// 32 rows/block (1024 blocks), 256 threads: tx 0..15 col-groups, ty 0..15 -> 2 rows
__global__ __launch_bounds__(256) void trig_kernel(
    const float* __restrict__ xfc, const int* __restrict__ head_idx,
    const float* __restrict__ Wt, const float* __restrict__ bt,
    float* __restrict__ logits, float* __restrict__ hat)
{
    __shared__ float Xs[32 * 36];   // [kk][row], 32 rows + 4 pad
    __shared__ float Ws[32 * 80];   // [kk][n], n>=68 zero
    __shared__ int srow[32];
    const int t = threadIdx.x;
    const int s0 = blockIdx.x * 32;
    if (t < 32) {
        int sg = s0 + t;
        int b = sg >> 9;
        srow[t] = (b << 9) + head_idx[sg];
    }
    __syncthreads();
    const int tx = t & 15, ty = t >> 4;
    float acc[2][5];
#pragma unroll
    for (int i = 0; i < 2; ++i)
#pragma unroll
        for (int m = 0; m < 5; ++m) acc[i][m] = 0.f;

    for (int k0 = 0; k0 < DB; k0 += 32) {
        // stage X: 32 rows x 32 k = 256 float4, 1/thread
        {
            int r = t >> 3;
            int c4 = (t & 7) << 2;
            float4 v = *reinterpret_cast<const float4*>(xfc + (size_t)srow[r] * DB + k0 + c4);
            Xs[(c4 + 0) * 36 + r] = v.x;
            Xs[(c4 + 1) * 36 + r] = v.y;
            Xs[(c4 + 2) * 36 + r] = v.z;
            Xs[(c4 + 3) * 36 + r] = v.w;
        }
        // stage W^T: 32 k x 80 n = 2560, 10/thread
#pragma unroll
        for (int i = 0; i < 10; ++i) {
            int e = t + i * 256;
            int kk = e & 31;
            int n = e >> 5;
            float v = (n < TT) ? Wt[(size_t)n * DB + k0 + kk] : 0.f;
            Ws[kk * 80 + n] = v;
        }
        __syncthreads();
#pragma unroll
        for (int kk = 0; kk < 32; ++kk) {
            v2f xa = *reinterpret_cast<const v2f*>(Xs + kk * 36 + ty * 2);
            float w[5];
#pragma unroll
            for (int m = 0; m < 5; ++m) w[m] = Ws[kk * 80 + tx + 16 * m];
#pragma unroll
            for (int m = 0; m < 5; ++m) {
                acc[0][m] += xa.x * w[m];
                acc[1][m] += xa.y * w[m];
            }
        }
        __syncthreads();
    }
#pragma unroll
    for (int i = 0; i < 2; ++i) {
        int row = s0 + ty * 2 + i;
        float bestv = -1e38f;
        int besti = 0;
#pragma unroll
        for (int m = 0; m < 5; ++m) {
            int col = tx + 16 * m;
            float v = -1e38f;
            if (col < TT) {
                v = acc[i][m] + bt[col];
                logits[(size_t)row * TT + col] = v;
            }
            if (v > bestv) { bestv = v; besti = col; }
        }
#pragma unroll
        for (int off = 8; off > 0; off >>= 1) {
            float ov = __shfl_xor(bestv, off, 16);
            int oi = __shfl_xor(besti, off, 16);
            if (ov > bestv || (ov == bestv && oi < besti)) { bestv = ov; besti = oi; }
        }
        if (tx == 0) hat[row] = (float)besti;
    }
}

// ---------------- K3a: span-mean pooling -> pooled[64][24][768]
__global__ __launch_bounds__(256) void pool_kernel(
    const float* __restrict__ xfc, const int* __restrict__ head_idx,
    const int* __restrict__ cand_spans, const int* __restrict__ trig_spans,
    float* __restrict__ pooled)
{
    const int b = blockIdx.x;
    __shared__ int rows_s[24][8];
    __shared__ int lens[24];
    __shared__ float invlen[24];
    const int t = threadIdx.x;
    if (t < 24) {
        const int* sp = (t < 8) ? (trig_spans + (b * 8 + t) * 2)
                                : (cand_spans + (b * 16 + (t - 8)) * 2);
        int st = sp[0], en = sp[1];
        int len = en - st;
        if (len < 0) len = 0;
        if (len > 8) len = 8;
        lens[t] = len;
        invlen[t] = 1.f / (float)(len > 0 ? len : 1);
        for (int p = 0; p < len; ++p)
            rows_s[t][p] = (b << 9) + head_idx[(b << 9) + st + p];
    }
    __syncthreads();
    for (int idx = t; idx < 24 * DB; idx += 256) {
        int n = idx / DB;
        int d = idx - n * DB;
        int len = lens[n];
        float s = 0.f;
        for (int p = 0; p < len; ++p)
            s += xfc[(size_t)rows_s[n][p] * DB + d];
        pooled[((size_t)b * 24 + n) * DB + d] = s * invlen[n];
    }
}

// ---------------- K3b: argument_hidden broadcast write [64][8][16][1536]
__global__ __launch_bounds__(256) void arg_kernel(
    const float* __restrict__ pooled, float* __restrict__ out2)
{
    int g = blockIdx.x * 256 + threadIdx.x;
    int b = g / 49152;
    int rem = g - b * 49152;
    int pair = rem / 384;
    int off4 = rem - pair * 384;
    int ti = pair >> 4;
    int c = pair & 15;
    int col = off4 << 2;
    const float* src;
    if (col < DB) src = pooled + ((size_t)(b * 24 + ti)) * DB + col;
    else          src = pooled + ((size_t)(b * 24 + 8 + c)) * DB + (col - DB);
    float4 v = *reinterpret_cast<const float4*>(src);
    *reinterpret_cast<float4*>(out2 + ((size_t)g << 2)) = v;
}

extern "C" void kernel_launch(void* const* d_in, const int* in_sizes, int n_in,
                              void* d_out, int out_size, void* d_ws, size_t ws_size,
                              hipStream_t stream)
{
    const float* enc   = (const float*)d_in[0];
    const float* table = (const float*)d_in[1];
    const float* fc1w  = (const float*)d_in[2];
    const float* fc1b  = (const float*)d_in[3];
    const float* trigw = (const float*)d_in[4];
    const float* trigb = (const float*)d_in[5];
    const int*   ex    = (const int*)d_in[6];
    const int*   hidx  = (const int*)d_in[7];
    const int*   cspan = (const int*)d_in[8];
    const int*   tspan = (const int*)d_in[9];

    float* out0 = (float*)d_out;
    float* out1 = out0 + (size_t)BS_TOTAL * TT;
    float* out2 = out1 + BS_TOTAL;

    float* ws_ent  = (float*)d_ws;
    float* ws_xfc  = ws_ent + (size_t)BS_TOTAL * EPAD;
    float* ws_pool = ws_xfc + (size_t)BS_TOTAL * DB;

    ent_kernel<<<dim3(BS_TOTAL * EPAD / 256), dim3(256), 0, stream>>>(ex, table, ws_ent);
    fc1_gemm<<<dim3(DB / 128, BS_TOTAL / 128), dim3(256), 0, stream>>>(enc, ws_ent, fc1w, fc1b, ws_xfc);
    trig_kernel<<<dim3(BS_TOTAL / 32), dim3(256), 0, stream>>>(ws_xfc, hidx, trigw, trigb, out0, out1);
    pool_kernel<<<dim3(64), dim3(256), 0, stream>>>(ws_xfc, hidx, cspan, tspan, ws_pool);
    arg_kernel<<<dim3(3145728 / 256), dim3(256), 0, stream>>>(ws_pool, out2);
}